// Round 13
// baseline (152.318 us; speedup 1.0000x reference)
//
#include <hip/hip_runtime.h>
#include <hip/hip_bf16.h>

typedef __attribute__((ext_vector_type(8))) short short8;
typedef __attribute__((ext_vector_type(4))) short short4v;
typedef __attribute__((ext_vector_type(4))) float f32x4;
typedef __attribute__((ext_vector_type(16))) float f32x16;
typedef __attribute__((ext_vector_type(4))) int int4v;
typedef __attribute__((ext_vector_type(2))) int int2v;

#define DEV static __device__ __forceinline__

constexpr int S_LEN   = 2048;
constexpr int DMODEL  = 1024;
constexpr int NHEAD   = 16;
constexpr int DHEAD   = 64;
constexpr int NBATCH  = 2;
constexpr int BHN     = NBATCH * NHEAD;   // 32
constexpr int MROWS   = NBATCH * S_LEN;   // 4096
constexpr int NDIM    = DMODEL;

// Q pre-scale: (1/8)/ln2 -> scores in log2 domain (native v_exp_f32 softmax)
constexpr float QSCALE = 0.125f * 1.442695041f;

DEV unsigned short f2b(float f) {
  __hip_bfloat16 h = __float2bfloat16(f);
  return __builtin_bit_cast(unsigned short, h);
}
DEV unsigned pk2(float a, float b) {
  return (unsigned)f2b(a) | ((unsigned)f2b(b) << 16);
}
DEV short8 ld8(const void* p) {
  return *reinterpret_cast<const short8*>(p);
}
DEV f32x4 mfma16(short8 a, short8 b, f32x4 c) {
  return __builtin_amdgcn_mfma_f32_16x16x32_bf16(a, b, c, 0, 0, 0);
}
DEV f32x16 mfma32(short8 a, short8 b, f32x16 c) {
  return __builtin_amdgcn_mfma_f32_32x32x16_bf16(a, b, c, 0, 0, 0);
}
DEV void gload16(const void* g, void* l) {
  __builtin_amdgcn_global_load_lds(
      (const __attribute__((address_space(1))) unsigned*)g,
      (__attribute__((address_space(3))) unsigned*)l, 16, 0, 0);
}
// native 2^x (v_exp_f32). libm exp2f is a multi-instruction OCML call --
// measured +14 us on attn in round 11.
DEV float exp2n(float x) {
#if __has_builtin(__builtin_amdgcn_exp2f)
  return __builtin_amdgcn_exp2f(x);
#else
  float r;
  asm("v_exp_f32 %0, %1" : "=v"(r) : "v"(x));
  return r;
#endif
}

// ---------------------------------------------------------------------------
// fp32 -> bf16 conversion pass (memory-bound, ~96 MB traffic)
// ---------------------------------------------------------------------------
struct CvtArgs {
  const float* src[7];
  unsigned short* dst[7];
  int n4[7];
};

__global__ __launch_bounds__(256) void cvt_bf16(CvtArgs c) {
  const int seg = blockIdx.y;
  const float* __restrict__ s = c.src[seg];
  unsigned short* __restrict__ d = c.dst[seg];
  const int n4 = c.n4[seg];
  for (int i = blockIdx.x * 256 + threadIdx.x; i < n4; i += gridDim.x * 256) {
    f32x4 v = reinterpret_cast<const f32x4*>(s)[i];
    short4v r;
    r[0] = (short)f2b(v[0]); r[1] = (short)f2b(v[1]);
    r[2] = (short)f2b(v[2]); r[3] = (short)f2b(v[3]);
    reinterpret_cast<short4v*>(d)[i] = r;
  }
}

// ---------------------------------------------------------------------------
// bf16 NT GEMM: round-12 structure (2-buffer, one __syncthreads/iter,
// C++ ds reads, conflict-free swizzle chunk ^= (row>>1)&3, 24 KB LDS ->
// 6 blocks/CU) + T1 bijective XCD clustering: 1D grid, remapped so each
// XCD owns contiguous (z,bm) groups -> the 16 bn-blocks sharing an A-panel
// run on ONE XCD; A staged from L2 (~200cy) instead of L3/HBM (~500-900cy).
// 128x64 tile, BK=32. C[row,col] = sum_k A[row,k]*W[col,k] + bia[col]
// ---------------------------------------------------------------------------
struct GB {
  const unsigned short* A[3];
  const unsigned short* W[3];
  const float* bia[3];
  void* out[3];
  int epi[3];   // 0=Q(scaled, exp2 domain) 1=K 2=V(transposed) 3=final(fp32)
};

__global__ __launch_bounds__(256, 4) void gemm_bf16(GB g) {
  // T1: bid -> xcd-contiguous swizzled id (grid is a multiple of 8).
  // swz order: [z][bm][bn] with bn fastest; each XCD gets gridDim.x/8
  // consecutive swz -> whole (z,bm) groups (16 blocks) per XCD.
  const int cpx = gridDim.x >> 3;
  const int swz = (blockIdx.x & 7) * cpx + (blockIdx.x >> 3);
  const int z   = swz >> 9;          // 512 blocks per z
  const int rem = swz & 511;
  const int bm  = rem >> 4, bn = rem & 15;

  const unsigned short* __restrict__ A = g.A[z];
  const unsigned short* __restrict__ W = g.W[z];
  const float* __restrict__ bia = g.bia[z];
  const int epi = g.epi[z];
  const int tid = threadIdx.x, lane = tid & 63, wid = tid >> 6;
  const int wr = wid >> 1, wc = wid & 1;          // 2x2 waves: 64x32 each
  const int fr = lane & 15, gq = lane >> 4;

  __shared__ unsigned short As[2][128][32];   // 8 KB x2
  __shared__ unsigned short Bs[2][64][32];    // 4 KB x2

  f32x4 acc[4][2] = {};

  const int srow = lane >> 2;
  const int scol = ((lane & 3) ^ ((srow >> 1) & 3)) * 16;
  const char* aS = (const char*)A + (size_t)(bm * 128 + wid * 32 + srow) * 2048 + scol;
  const char* bS = (const char*)W + (size_t)(bn * 64 + wid * 16 + srow) * 2048 + scol;

  auto stage = [&](int buf, int kt) {
    const int ko = kt * 64;
    char* a0 = (char*)As[buf] + wid * 2048;
    char* b0 = (char*)Bs[buf] + wid * 1024;
    gload16(aS + ko, a0);
    gload16(aS + (size_t)16 * 2048 + ko, a0 + 1024);
    gload16(bS + ko, b0);
  };

  // (row>>1)&3 == (fr>>1)&3 for every fragment row (offsets are mult. of 8)
  const int rdo = (gq ^ ((fr >> 1) & 3)) * 8;

  stage(0, 0);
  __syncthreads();
  for (int kt = 0; kt < 32; ++kt) {
    const int buf = kt & 1;
    if (kt + 1 < 32) stage(buf ^ 1, kt + 1);
    short8 af[4], bf4[2];
#pragma unroll
    for (int i = 0; i < 4; ++i) af[i] = ld8(&As[buf][wr * 64 + i * 16 + fr][rdo]);
#pragma unroll
    for (int j = 0; j < 2; ++j) bf4[j] = ld8(&Bs[buf][wc * 32 + j * 16 + fr][rdo]);
#pragma unroll
    for (int i = 0; i < 4; ++i)
#pragma unroll
      for (int j = 0; j < 2; ++j)
        acc[i][j] = mfma16(af[i], bf4[j], acc[i][j]);
    __syncthreads();
  }

#pragma unroll
  for (int i = 0; i < 4; ++i) {
#pragma unroll
    for (int j = 0; j < 2; ++j) {
#pragma unroll
      for (int r = 0; r < 4; ++r) {
        const int row = bm * 128 + wr * 64 + i * 16 + gq * 4 + r;
        const int col = bn * 64 + wc * 32 + j * 16 + fr;
        float v = acc[i][j][r] + bia[col];
        if (epi == 3) {
          ((float*)g.out[z])[(size_t)row * NDIM + col] = v;
        } else {
          const int b = row >> 11, s = row & (S_LEN - 1);
          const int h = col >> 6,  dh = col & (DHEAD - 1);
          unsigned short* O = (unsigned short*)g.out[z];
          if (epi == 0)      O[((size_t)(b * NHEAD + h) * S_LEN + s) * DHEAD + dh] = f2b(v * QSCALE);
          else if (epi == 1) O[((size_t)(b * NHEAD + h) * S_LEN + s) * DHEAD + dh] = f2b(v);
          else               O[((size_t)(b * NHEAD + h) * DHEAD + dh) * S_LEN + s] = f2b(v);
        }
      }
    }
  }
}

// ---------------------------------------------------------------------------
// Flash attention (round-12, passing, unchanged): split-KV x2 in-block,
// fixed m=0 log2-domain softmax with native v_exp, exact merge.
// ---------------------------------------------------------------------------
__global__ __launch_bounds__(512, 2) void attn_fwd(
    const unsigned short* __restrict__ Qp,
    const unsigned short* __restrict__ Kp,
    const unsigned short* __restrict__ Vt,
    unsigned short* __restrict__ AO) {
  const int nb = (blockIdx.x & 7) * 64 + (blockIdx.x >> 3);
  const int qt = nb & 15, bh = nb >> 4;
  const int tid = threadIdx.x, lane = tid & 63, wid = tid >> 6;
  const int qw = wid & 3, hw = wid >> 2;
  const int ql = lane & 31, hi = lane >> 5, l7 = lane & 7, l3 = lane >> 3;

  const unsigned short* Qh = Qp + (size_t)bh * S_LEN * DHEAD;
  const char* Kh = (const char*)(Kp + (size_t)bh * S_LEN * DHEAD);
  const char* Vh = (const char*)(Vt + (size_t)bh * DHEAD * S_LEN);

  __shared__ unsigned short Klds[2][2][4096];   // [hw][buf] 32KB
  __shared__ unsigned short Vlds[2][2][4096];   // [hw][buf] 32KB

  const int q0 = qt * 128 + qw * 32;
  short8 qf[4];
#pragma unroll
  for (int d16 = 0; d16 < 4; ++d16)
    qf[d16] = ld8(Qh + (size_t)(q0 + ql) * DHEAD + d16 * 16 + hi * 8);

  const int swc = (l7 ^ l3) << 4;
  const char* kS = Kh + (size_t)hw * 16 * 8192 + (qw * 16 + l3) * 128 + swc;
  const char* vS = Vh + (size_t)hw * 16 * 128 + (qw * 16 + l3) * 4096 + swc;
  char* kD0 = (char*)Klds[hw][0] + qw * 2048;
  char* vD0 = (char*)Vlds[hw][0] + qw * 2048;
  char* kD1 = (char*)Klds[hw][1] + qw * 2048;
  char* vD1 = (char*)Vlds[hw][1] + qw * 2048;

  int xo[4];
#pragma unroll
  for (int j = 0; j < 4; ++j) xo[j] = ((j * 2 + hi) ^ l7) << 4;

  float lacc[8] = {};
  f32x16 o0 = {}, o1 = {};

  gload16(kS, kD0); gload16(kS + 1024, kD0 + 1024);
  gload16(vS, vD0); gload16(vS + 32768, vD0 + 1024);
  __syncthreads();

  constexpr int NT = S_LEN / 64 / 2;   // 16 tiles per half
  for (int kt = 0; kt < NT; ++kt) {
    const int buf = kt & 1;
    if (kt + 1 < NT) {
      const char* kn = kS + (kt + 1) * 8192;
      const char* vn = vS + (kt + 1) * 128;
      char* kD = buf ? kD0 : kD1;
      char* vD = buf ? vD0 : vD1;
      gload16(kn, kD); gload16(kn + 1024, kD + 1024);
      gload16(vn, vD); gload16(vn + 32768, vD + 1024);
    }
    const char* kb = (const char*)Klds[hw][buf] + ql * 128;
    const char* vb = (const char*)Vlds[hw][buf] + ql * 128;

    f32x16 st0 = {}, st1 = {};
#pragma unroll
    for (int d16 = 0; d16 < 4; ++d16) {
      short8 k0 = ld8(kb + xo[d16]);
      short8 k1 = ld8(kb + 4096 + xo[d16]);
      st0 = mfma32(k0, qf[d16], st0);
      st1 = mfma32(k1, qf[d16], st1);
    }

    // P = 2^s (fixed m=0), lane-local l accumulation
#pragma unroll
    for (int r = 0; r < 16; ++r) {
      st0[r] = exp2n(st0[r]);
      st1[r] = exp2n(st1[r]);
    }
#pragma unroll
    for (int r = 0; r < 8; ++r)
      lacc[r] += (st0[r] + st0[r + 8]) + (st1[r] + st1[r + 8]);

#pragma unroll
    for (int ks = 0; ks < 4; ++ks) {
      const f32x16& p = (ks < 2) ? st0 : st1;
      const int a = 8 * (ks & 1);
      unsigned w0 = pk2(p[a + 0], p[a + 1]);
      unsigned w1 = pk2(p[a + 2], p[a + 3]);
      unsigned w2 = pk2(p[a + 4], p[a + 5]);
      unsigned w3 = pk2(p[a + 6], p[a + 7]);
      unsigned x0 = (unsigned)__shfl_xor((int)w0, 32);
      unsigned x1 = (unsigned)__shfl_xor((int)w1, 32);
      unsigned x2 = (unsigned)__shfl_xor((int)w2, 32);
      unsigned x3 = (unsigned)__shfl_xor((int)w3, 32);
      int4v pi;
      pi[0] = (int)(hi ? x2 : w0);
      pi[1] = (int)(hi ? x3 : w1);
      pi[2] = (int)(hi ? w2 : x0);
      pi[3] = (int)(hi ? w3 : x1);
      short8 pb = __builtin_bit_cast(short8, pi);
      short8 v0 = ld8(vb + xo[ks]);
      short8 v1 = ld8(vb + 4096 + xo[ks]);
      o0 = mfma32(v0, pb, o0);
      o1 = mfma32(v1, pb, o1);
    }
    __syncthreads();
  }

  // per-half l: tree over 8 + one cross-half exchange
#pragma unroll
  for (int s = 4; s; s >>= 1)
#pragma unroll
    for (int r = 0; r < s; ++r) lacc[r] += lacc[r + s];
  float l = lacc[0] + __shfl_xor(lacc[0], 32);

  // exact merge across KV halves: O = Oa + Ob, l = la + lb
  float* Kf = (float*)&Klds[0][0][0];
  float* Vf = (float*)&Vlds[0][0][0];
  if (hw == 1) {
#pragma unroll
    for (int r = 0; r < 16; ++r) {
      Kf[qw * 2048 + r * 64 + lane]        = o0[r];
      Kf[qw * 2048 + (16 + r) * 64 + lane] = o1[r];
    }
    Vf[qw * 64 + lane] = l;
  }
  __syncthreads();
  if (hw == 0) {
    const float inv = 1.f / (l + Vf[qw * 64 + lane]);
    const int b = bh >> 4, h = bh & 15;
    unsigned short* Op = AO + ((size_t)(b * S_LEN + q0 + ql)) * DMODEL + h * DHEAD;
#pragma unroll
    for (int gidx = 0; gidx < 4; ++gidx) {
      float f0[4], f1[4];
#pragma unroll
      for (int r = 0; r < 4; ++r) {
        const int rr = gidx * 4 + r;
        f0[r] = (o0[rr] + Kf[qw * 2048 + rr * 64 + lane]) * inv;
        f1[r] = (o1[rr] + Kf[qw * 2048 + (16 + rr) * 64 + lane]) * inv;
      }
      int2v s0, s1;
      s0[0] = (int)pk2(f0[0], f0[1]); s0[1] = (int)pk2(f0[2], f0[3]);
      s1[0] = (int)pk2(f1[0], f1[1]); s1[1] = (int)pk2(f1[2], f1[3]);
      *reinterpret_cast<int2v*>(Op + 8 * gidx + 4 * hi)      = s0;
      *reinterpret_cast<int2v*>(Op + 32 + 8 * gidx + 4 * hi) = s1;
    }
  }
}

extern "C" void kernel_launch(void* const* d_in, const int* in_sizes, int n_in,
                              void* d_out, int out_size, void* d_ws, size_t ws_size,
                              hipStream_t stream) {
  const float* query = (const float*)d_in[0];
  const float* key   = (const float*)d_in[1];
  const float* value = (const float*)d_in[2];
  const float* Wq = (const float*)d_in[3];  const float* bq = (const float*)d_in[4];
  const float* Wk = (const float*)d_in[5];  const float* bk = (const float*)d_in[6];
  const float* Wv = (const float*)d_in[7];  const float* bv = (const float*)d_in[8];
  const float* Wo = (const float*)d_in[9];  const float* bo = (const float*)d_in[10];

  const size_t MB = 1024u * 1024u;
  unsigned short* Xb  = (unsigned short*)((char*)d_ws + 0 * MB);
  unsigned short* Wb  = (unsigned short*)((char*)d_ws + 24 * MB);
  unsigned short* Wob = (unsigned short*)((char*)d_ws + 30 * MB);
  unsigned short* Qp  = (unsigned short*)((char*)d_ws + 32 * MB);
  unsigned short* Kp  = (unsigned short*)((char*)d_ws + 40 * MB);
  unsigned short* Vt  = (unsigned short*)((char*)d_ws + 48 * MB);
  unsigned short* AOb = (unsigned short*)((char*)d_ws + 0 * MB);   // overlays Xb[query]

  const int NACT = MROWS * DMODEL;
  const int NWT  = DMODEL * DMODEL;

  CvtArgs ca;
  ca.src[0] = query; ca.dst[0] = Xb;            ca.n4[0] = NACT / 4;
  ca.src[1] = key;   ca.dst[1] = Xb + NACT;     ca.n4[1] = NACT / 4;
  ca.src[2] = value; ca.dst[2] = Xb + 2 * NACT; ca.n4[2] = NACT / 4;
  ca.src[3] = Wq;    ca.dst[3] = Wb;            ca.n4[3] = NWT / 4;
  ca.src[4] = Wk;    ca.dst[4] = Wb + NWT;      ca.n4[4] = NWT / 4;
  ca.src[5] = Wv;    ca.dst[5] = Wb + 2 * NWT;  ca.n4[5] = NWT / 4;
  ca.src[6] = Wo;    ca.dst[6] = Wob;           ca.n4[6] = NWT / 4;
  cvt_bf16<<<dim3(512, 7), 256, 0, stream>>>(ca);

  GB g1;
  g1.A[0] = Xb;            g1.A[1] = Xb + NACT; g1.A[2] = Xb + 2 * NACT;
  g1.W[0] = Wb;            g1.W[1] = Wb + NWT;  g1.W[2] = Wb + 2 * NWT;
  g1.bia[0] = bq;  g1.bia[1] = bk; g1.bia[2] = bv;
  g1.out[0] = Qp;  g1.out[1] = Kp; g1.out[2] = Vt;
  g1.epi[0] = 0;   g1.epi[1] = 1;  g1.epi[2] = 2;
  gemm_bf16<<<dim3(16 * 32 * 3), 256, 0, stream>>>(g1);

  attn_fwd<<<dim3(BHN * 16), 512, 0, stream>>>(Qp, Kp, Vt, AOb);

  GB g2 = {};
  g2.A[0] = AOb; g2.W[0] = Wob; g2.bia[0] = bo; g2.out[0] = d_out; g2.epi[0] = 3;
  gemm_bf16<<<dim3(16 * 32), 256, 0, stream>>>(g2);
}

// Round 14
// 151.959 us; speedup vs baseline: 1.0024x; 1.0024x over previous
//
#include <hip/hip_runtime.h>
#include <hip/hip_bf16.h>

typedef __attribute__((ext_vector_type(8))) short short8;
typedef __attribute__((ext_vector_type(4))) short short4v;
typedef __attribute__((ext_vector_type(4))) float f32x4;
typedef __attribute__((ext_vector_type(16))) float f32x16;
typedef __attribute__((ext_vector_type(4))) int int4v;
typedef __attribute__((ext_vector_type(2))) int int2v;

#define DEV static __device__ __forceinline__

constexpr int S_LEN   = 2048;
constexpr int DMODEL  = 1024;
constexpr int NHEAD   = 16;
constexpr int DHEAD   = 64;
constexpr int NBATCH  = 2;
constexpr int BHN     = NBATCH * NHEAD;   // 32
constexpr int MROWS   = NBATCH * S_LEN;   // 4096
constexpr int NDIM    = DMODEL;

// Q pre-scale: (1/8)/ln2 -> scores in log2 domain (native v_exp_f32 softmax)
constexpr float QSCALE = 0.125f * 1.442695041f;

DEV unsigned short f2b(float f) {
  __hip_bfloat16 h = __float2bfloat16(f);
  return __builtin_bit_cast(unsigned short, h);
}
DEV unsigned pk2(float a, float b) {
  return (unsigned)f2b(a) | ((unsigned)f2b(b) << 16);
}
DEV short8 ld8(const void* p) {
  return *reinterpret_cast<const short8*>(p);
}
DEV f32x4 mfma16(short8 a, short8 b, f32x4 c) {
  return __builtin_amdgcn_mfma_f32_16x16x32_bf16(a, b, c, 0, 0, 0);
}
DEV f32x16 mfma32(short8 a, short8 b, f32x16 c) {
  return __builtin_amdgcn_mfma_f32_32x32x16_bf16(a, b, c, 0, 0, 0);
}
DEV void gload16(const void* g, void* l) {
  __builtin_amdgcn_global_load_lds(
      (const __attribute__((address_space(1))) unsigned*)g,
      (__attribute__((address_space(3))) unsigned*)l, 16, 0, 0);
}
// native 2^x (v_exp_f32); libm exp2f is a slow OCML call (round-11 data)
DEV float exp2n(float x) {
#if __has_builtin(__builtin_amdgcn_exp2f)
  return __builtin_amdgcn_exp2f(x);
#else
  float r;
  asm("v_exp_f32 %0, %1" : "=v"(r) : "v"(x));
  return r;
#endif
}

// ---------------------------------------------------------------------------
// fp32 -> bf16 conversion pass (memory-bound, ~96 MB traffic)
// ---------------------------------------------------------------------------
struct CvtArgs {
  const float* src[7];
  unsigned short* dst[7];
  int n4[7];
};

__global__ __launch_bounds__(256) void cvt_bf16(CvtArgs c) {
  const int seg = blockIdx.y;
  const float* __restrict__ s = c.src[seg];
  unsigned short* __restrict__ d = c.dst[seg];
  const int n4 = c.n4[seg];
  for (int i = blockIdx.x * 256 + threadIdx.x; i < n4; i += gridDim.x * 256) {
    f32x4 v = reinterpret_cast<const f32x4*>(s)[i];
    short4v r;
    r[0] = (short)f2b(v[0]); r[1] = (short)f2b(v[1]);
    r[2] = (short)f2b(v[2]); r[3] = (short)f2b(v[3]);
    reinterpret_cast<short4v*>(d)[i] = r;
  }
}

// ---------------------------------------------------------------------------
// bf16 NT GEMM, 128x64 tile, BK=32, REGISTER-STAGED prefetch:
// global_load_dwordx4 -> VGPR (private: __syncthreads need NOT drain it;
// compiler emits per-reg vmcnt only before the consuming ds_write) ->
// ds_write_b128 next iter. Prefetch distance ~1.5 iters vs 0 for the
// global_load_lds+barrier structure (round-13 diagnosis: 4800 cyc/K-step
// critical path = same-step vmcnt(0) drain under 1536-block contention).
// Swizzle on the WRITE address (per-lane now): chunk ^= (row>>1)&3;
// reads keep the proven conflict-free rdo. LDS 24KB -> 6 blocks/CU.
// T1 XCD clustering kept (FETCH 101->23 MB, round 13).
// C[row,col] = sum_k A[row,k]*W[col,k] + bia[col]
// ---------------------------------------------------------------------------
struct GB {
  const unsigned short* A[3];
  const unsigned short* W[3];
  const float* bia[3];
  void* out[3];
  int epi[3];   // 0=Q(scaled, exp2 domain) 1=K 2=V(transposed) 3=final(fp32)
};

__global__ __launch_bounds__(256, 4) void gemm_bf16(GB g) {
  // T1: xcd-contiguous remap; swz order [z][bm][bn], bn fastest.
  const int cpx = gridDim.x >> 3;
  const int swz = (blockIdx.x & 7) * cpx + (blockIdx.x >> 3);
  const int z   = swz >> 9;          // 512 blocks per z
  const int rem = swz & 511;
  const int bm  = rem >> 4, bn = rem & 15;

  const unsigned short* __restrict__ A = g.A[z];
  const unsigned short* __restrict__ W = g.W[z];
  const float* __restrict__ bia = g.bia[z];
  const int epi = g.epi[z];
  const int tid = threadIdx.x, lane = tid & 63, wid = tid >> 6;
  const int wr = wid >> 1, wc = wid & 1;          // 2x2 waves: 64x32 each
  const int fr = lane & 15, gq = lane >> 4;

  __shared__ unsigned short As[2][128][32];   // 8 KB x2
  __shared__ unsigned short Bs[2][64][32];    // 4 KB x2

  f32x4 acc[4][2] = {};

  // staging geometry: lane covers row (lane>>2), 16B chunk (lane&3);
  // global source UNSWIZZLED (fully coalesced 64B rows);
  // LDS write address swizzled: chunk ^= (row>>1)&3 (involution, and
  // (srow+16) has the same (row>>1)&3 parity class per 2-row step? note
  // ((srow+16)>>1)&3 == ((srow>>1)+8)&3 == (srow>>1)&3  -> same swizzle).
  const int srow = lane >> 2;
  const int c4   = lane & 3;
  const char* aS = (const char*)A + (size_t)(bm * 128 + wid * 32 + srow) * 2048 + c4 * 16;
  const char* bS = (const char*)W + (size_t)(bn * 64 + wid * 16 + srow) * 2048 + c4 * 16;
  const int swc = (c4 ^ ((srow >> 1) & 3)) * 16;
  char* aW0 = (char*)&As[0][wid * 32 + srow][0] + swc;
  char* aW1 = (char*)&As[0][wid * 32 + 16 + srow][0] + swc;
  char* bW  = (char*)&Bs[0][wid * 16 + srow][0] + swc;

  int4v ra0, ra1, rb;   // prefetch registers (live across iterations)
  auto LOAD = [&](int kt) {
    const int ko = kt * 64;
    ra0 = *reinterpret_cast<const int4v*>(aS + ko);
    ra1 = *reinterpret_cast<const int4v*>(aS + (size_t)16 * 2048 + ko);
    rb  = *reinterpret_cast<const int4v*>(bS + ko);
  };
  auto WRITE = [&](int buf) {
    *reinterpret_cast<int4v*>(aW0 + buf * 8192) = ra0;
    *reinterpret_cast<int4v*>(aW1 + buf * 8192) = ra1;
    *reinterpret_cast<int4v*>(bW  + buf * 4096) = rb;
  };

  // read offset: gq ^ ((fr>>1)&3) — conflict-free (round-9 verified)
  const int rdo = (gq ^ ((fr >> 1) & 3)) * 8;

  LOAD(0);
  WRITE(0);
  LOAD(1);
  __syncthreads();
  for (int kt = 0; kt < 32; ++kt) {
    const int buf = kt & 1;
    if (kt + 1 < 32) WRITE(buf ^ 1);     // regs loaded last iter (vmcnt(k) auto)
    if (kt + 2 < 32) LOAD(kt + 2);       // private: barrier won't drain these
    short8 af[4], bf4[2];
#pragma unroll
    for (int i = 0; i < 4; ++i) af[i] = ld8(&As[buf][wr * 64 + i * 16 + fr][rdo]);
#pragma unroll
    for (int j = 0; j < 2; ++j) bf4[j] = ld8(&Bs[buf][wc * 32 + j * 16 + fr][rdo]);
#pragma unroll
    for (int i = 0; i < 4; ++i)
#pragma unroll
      for (int j = 0; j < 2; ++j)
        acc[i][j] = mfma16(af[i], bf4[j], acc[i][j]);
    __syncthreads();
  }

#pragma unroll
  for (int i = 0; i < 4; ++i) {
#pragma unroll
    for (int j = 0; j < 2; ++j) {
#pragma unroll
      for (int r = 0; r < 4; ++r) {
        const int row = bm * 128 + wr * 64 + i * 16 + gq * 4 + r;
        const int col = bn * 64 + wc * 32 + j * 16 + fr;
        float v = acc[i][j][r] + bia[col];
        if (epi == 3) {
          ((float*)g.out[z])[(size_t)row * NDIM + col] = v;
        } else {
          const int b = row >> 11, s = row & (S_LEN - 1);
          const int h = col >> 6,  dh = col & (DHEAD - 1);
          unsigned short* O = (unsigned short*)g.out[z];
          if (epi == 0)      O[((size_t)(b * NHEAD + h) * S_LEN + s) * DHEAD + dh] = f2b(v * QSCALE);
          else if (epi == 1) O[((size_t)(b * NHEAD + h) * S_LEN + s) * DHEAD + dh] = f2b(v);
          else               O[((size_t)(b * NHEAD + h) * DHEAD + dh) * S_LEN + s] = f2b(v);
        }
      }
    }
  }
}

// ---------------------------------------------------------------------------
// Flash attention (round-12/13, passing, unchanged): split-KV x2 in-block,
// fixed m=0 log2-domain softmax with native v_exp, exact merge.
// ---------------------------------------------------------------------------
__global__ __launch_bounds__(512, 2) void attn_fwd(
    const unsigned short* __restrict__ Qp,
    const unsigned short* __restrict__ Kp,
    const unsigned short* __restrict__ Vt,
    unsigned short* __restrict__ AO) {
  const int nb = (blockIdx.x & 7) * 64 + (blockIdx.x >> 3);
  const int qt = nb & 15, bh = nb >> 4;
  const int tid = threadIdx.x, lane = tid & 63, wid = tid >> 6;
  const int qw = wid & 3, hw = wid >> 2;
  const int ql = lane & 31, hi = lane >> 5, l7 = lane & 7, l3 = lane >> 3;

  const unsigned short* Qh = Qp + (size_t)bh * S_LEN * DHEAD;
  const char* Kh = (const char*)(Kp + (size_t)bh * S_LEN * DHEAD);
  const char* Vh = (const char*)(Vt + (size_t)bh * DHEAD * S_LEN);

  __shared__ unsigned short Klds[2][2][4096];   // [hw][buf] 32KB
  __shared__ unsigned short Vlds[2][2][4096];   // [hw][buf] 32KB

  const int q0 = qt * 128 + qw * 32;
  short8 qf[4];
#pragma unroll
  for (int d16 = 0; d16 < 4; ++d16)
    qf[d16] = ld8(Qh + (size_t)(q0 + ql) * DHEAD + d16 * 16 + hi * 8);

  const int swc = (l7 ^ l3) << 4;
  const char* kS = Kh + (size_t)hw * 16 * 8192 + (qw * 16 + l3) * 128 + swc;
  const char* vS = Vh + (size_t)hw * 16 * 128 + (qw * 16 + l3) * 4096 + swc;
  char* kD0 = (char*)Klds[hw][0] + qw * 2048;
  char* vD0 = (char*)Vlds[hw][0] + qw * 2048;
  char* kD1 = (char*)Klds[hw][1] + qw * 2048;
  char* vD1 = (char*)Vlds[hw][1] + qw * 2048;

  int xo[4];
#pragma unroll
  for (int j = 0; j < 4; ++j) xo[j] = ((j * 2 + hi) ^ l7) << 4;

  float lacc[8] = {};
  f32x16 o0 = {}, o1 = {};

  gload16(kS, kD0); gload16(kS + 1024, kD0 + 1024);
  gload16(vS, vD0); gload16(vS + 32768, vD0 + 1024);
  __syncthreads();

  constexpr int NT = S_LEN / 64 / 2;   // 16 tiles per half
  for (int kt = 0; kt < NT; ++kt) {
    const int buf = kt & 1;
    if (kt + 1 < NT) {
      const char* kn = kS + (kt + 1) * 8192;
      const char* vn = vS + (kt + 1) * 128;
      char* kD = buf ? kD0 : kD1;
      char* vD = buf ? vD0 : vD1;
      gload16(kn, kD); gload16(kn + 1024, kD + 1024);
      gload16(vn, vD); gload16(vn + 32768, vD + 1024);
    }
    const char* kb = (const char*)Klds[hw][buf] + ql * 128;
    const char* vb = (const char*)Vlds[hw][buf] + ql * 128;

    f32x16 st0 = {}, st1 = {};
#pragma unroll
    for (int d16 = 0; d16 < 4; ++d16) {
      short8 k0 = ld8(kb + xo[d16]);
      short8 k1 = ld8(kb + 4096 + xo[d16]);
      st0 = mfma32(k0, qf[d16], st0);
      st1 = mfma32(k1, qf[d16], st1);
    }

    // P = 2^s (fixed m=0), lane-local l accumulation
#pragma unroll
    for (int r = 0; r < 16; ++r) {
      st0[r] = exp2n(st0[r]);
      st1[r] = exp2n(st1[r]);
    }
#pragma unroll
    for (int r = 0; r < 8; ++r)
      lacc[r] += (st0[r] + st0[r + 8]) + (st1[r] + st1[r + 8]);

#pragma unroll
    for (int ks = 0; ks < 4; ++ks) {
      const f32x16& p = (ks < 2) ? st0 : st1;
      const int a = 8 * (ks & 1);
      unsigned w0 = pk2(p[a + 0], p[a + 1]);
      unsigned w1 = pk2(p[a + 2], p[a + 3]);
      unsigned w2 = pk2(p[a + 4], p[a + 5]);
      unsigned w3 = pk2(p[a + 6], p[a + 7]);
      unsigned x0 = (unsigned)__shfl_xor((int)w0, 32);
      unsigned x1 = (unsigned)__shfl_xor((int)w1, 32);
      unsigned x2 = (unsigned)__shfl_xor((int)w2, 32);
      unsigned x3 = (unsigned)__shfl_xor((int)w3, 32);
      int4v pi;
      pi[0] = (int)(hi ? x2 : w0);
      pi[1] = (int)(hi ? x3 : w1);
      pi[2] = (int)(hi ? w2 : x0);
      pi[3] = (int)(hi ? w3 : x1);
      short8 pb = __builtin_bit_cast(short8, pi);
      short8 v0 = ld8(vb + xo[ks]);
      short8 v1 = ld8(vb + 4096 + xo[ks]);
      o0 = mfma32(v0, pb, o0);
      o1 = mfma32(v1, pb, o1);
    }
    __syncthreads();
  }

  // per-half l: tree over 8 + one cross-half exchange
#pragma unroll
  for (int s = 4; s; s >>= 1)
#pragma unroll
    for (int r = 0; r < s; ++r) lacc[r] += lacc[r + s];
  float l = lacc[0] + __shfl_xor(lacc[0], 32);

  // exact merge across KV halves: O = Oa + Ob, l = la + lb
  float* Kf = (float*)&Klds[0][0][0];
  float* Vf = (float*)&Vlds[0][0][0];
  if (hw == 1) {
#pragma unroll
    for (int r = 0; r < 16; ++r) {
      Kf[qw * 2048 + r * 64 + lane]        = o0[r];
      Kf[qw * 2048 + (16 + r) * 64 + lane] = o1[r];
    }
    Vf[qw * 64 + lane] = l;
  }
  __syncthreads();
  if (hw == 0) {
    const float inv = 1.f / (l + Vf[qw * 64 + lane]);
    const int b = bh >> 4, h = bh & 15;
    unsigned short* Op = AO + ((size_t)(b * S_LEN + q0 + ql)) * DMODEL + h * DHEAD;
#pragma unroll
    for (int gidx = 0; gidx < 4; ++gidx) {
      float f0[4], f1[4];
#pragma unroll
      for (int r = 0; r < 4; ++r) {
        const int rr = gidx * 4 + r;
        f0[r] = (o0[rr] + Kf[qw * 2048 + rr * 64 + lane]) * inv;
        f1[r] = (o1[rr] + Kf[qw * 2048 + (16 + rr) * 64 + lane]) * inv;
      }
      int2v s0, s1;
      s0[0] = (int)pk2(f0[0], f0[1]); s0[1] = (int)pk2(f0[2], f0[3]);
      s1[0] = (int)pk2(f1[0], f1[1]); s1[1] = (int)pk2(f1[2], f1[3]);
      *reinterpret_cast<int2v*>(Op + 8 * gidx + 4 * hi)      = s0;
      *reinterpret_cast<int2v*>(Op + 32 + 8 * gidx + 4 * hi) = s1;
    }
  }
}

extern "C" void kernel_launch(void* const* d_in, const int* in_sizes, int n_in,
                              void* d_out, int out_size, void* d_ws, size_t ws_size,
                              hipStream_t stream) {
  const float* query = (const float*)d_in[0];
  const float* key   = (const float*)d_in[1];
  const float* value = (const float*)d_in[2];
  const float* Wq = (const float*)d_in[3];  const float* bq = (const float*)d_in[4];
  const float* Wk = (const float*)d_in[5];  const float* bk = (const float*)d_in[6];
  const float* Wv = (const float*)d_in[7];  const float* bv = (const float*)d_in[8];
  const float* Wo = (const float*)d_in[9];  const float* bo = (const float*)d_in[10];

  const size_t MB = 1024u * 1024u;
  unsigned short* Xb  = (unsigned short*)((char*)d_ws + 0 * MB);
  unsigned short* Wb  = (unsigned short*)((char*)d_ws + 24 * MB);
  unsigned short* Wob = (unsigned short*)((char*)d_ws + 30 * MB);
  unsigned short* Qp  = (unsigned short*)((char*)d_ws + 32 * MB);
  unsigned short* Kp  = (unsigned short*)((char*)d_ws + 40 * MB);
  unsigned short* Vt  = (unsigned short*)((char*)d_ws + 48 * MB);
  unsigned short* AOb = (unsigned short*)((char*)d_ws + 0 * MB);   // overlays Xb[query]

  const int NACT = MROWS * DMODEL;
  const int NWT  = DMODEL * DMODEL;

  CvtArgs ca;
  ca.src[0] = query; ca.dst[0] = Xb;            ca.n4[0] = NACT / 4;
  ca.src[1] = key;   ca.dst[1] = Xb + NACT;     ca.n4[1] = NACT / 4;
  ca.src[2] = value; ca.dst[2] = Xb + 2 * NACT; ca.n4[2] = NACT / 4;
  ca.src[3] = Wq;    ca.dst[3] = Wb;            ca.n4[3] = NWT / 4;
  ca.src[4] = Wk;    ca.dst[4] = Wb + NWT;      ca.n4[4] = NWT / 4;
  ca.src[5] = Wv;    ca.dst[5] = Wb + 2 * NWT;  ca.n4[5] = NWT / 4;
  ca.src[6] = Wo;    ca.dst[6] = Wob;           ca.n4[6] = NWT / 4;
  cvt_bf16<<<dim3(512, 7), 256, 0, stream>>>(ca);

  GB g1;
  g1.A[0] = Xb;            g1.A[1] = Xb + NACT; g1.A[2] = Xb + 2 * NACT;
  g1.W[0] = Wb;            g1.W[1] = Wb + NWT;  g1.W[2] = Wb + 2 * NWT;
  g1.bia[0] = bq;  g1.bia[1] = bk; g1.bia[2] = bv;
  g1.out[0] = Qp;  g1.out[1] = Kp; g1.out[2] = Vt;
  g1.epi[0] = 0;   g1.epi[1] = 1;  g1.epi[2] = 2;
  gemm_bf16<<<dim3(16 * 32 * 3), 256, 0, stream>>>(g1);

  attn_fwd<<<dim3(BHN * 16), 512, 0, stream>>>(Qp, Kp, Vt, AOb);

  GB g2 = {};
  g2.A[0] = AOb; g2.W[0] = Wob; g2.bia[0] = bo; g2.out[0] = d_out; g2.epi[0] = 3;
  gemm_bf16<<<dim3(16 * 32), 256, 0, stream>>>(g2);
}

// Round 15
// 145.075 us; speedup vs baseline: 1.0499x; 1.0474x over previous
//
#include <hip/hip_runtime.h>
#include <hip/hip_bf16.h>

typedef __attribute__((ext_vector_type(8))) short short8;
typedef __attribute__((ext_vector_type(4))) short short4v;
typedef __attribute__((ext_vector_type(4))) float f32x4;
typedef __attribute__((ext_vector_type(16))) float f32x16;
typedef __attribute__((ext_vector_type(4))) int int4v;
typedef __attribute__((ext_vector_type(2))) int int2v;

#define DEV static __device__ __forceinline__

constexpr int S_LEN   = 2048;
constexpr int DMODEL  = 1024;
constexpr int NHEAD   = 16;
constexpr int DHEAD   = 64;
constexpr int NBATCH  = 2;
constexpr int BHN     = NBATCH * NHEAD;   // 32
constexpr int MROWS   = NBATCH * S_LEN;   // 4096
constexpr int NDIM    = DMODEL;

// Q pre-scale: (1/8)/ln2 -> scores in log2 domain (native v_exp_f32 softmax)
constexpr float QSCALE = 0.125f * 1.442695041f;

DEV unsigned short f2b(float f) {
  __hip_bfloat16 h = __float2bfloat16(f);
  return __builtin_bit_cast(unsigned short, h);
}
DEV unsigned pk2(float a, float b) {
  return (unsigned)f2b(a) | ((unsigned)f2b(b) << 16);
}
DEV short8 ld8(const void* p) {
  return *reinterpret_cast<const short8*>(p);
}
DEV f32x4 mfma16(short8 a, short8 b, f32x4 c) {
  return __builtin_amdgcn_mfma_f32_16x16x32_bf16(a, b, c, 0, 0, 0);
}
DEV f32x16 mfma32(short8 a, short8 b, f32x16 c) {
  return __builtin_amdgcn_mfma_f32_32x32x16_bf16(a, b, c, 0, 0, 0);
}
DEV void gload16(const void* g, void* l) {
  __builtin_amdgcn_global_load_lds(
      (const __attribute__((address_space(1))) unsigned*)g,
      (__attribute__((address_space(3))) unsigned*)l, 16, 0, 0);
}
// native 2^x (v_exp_f32); libm exp2f is a slow OCML call (round-11 data)
DEV float exp2n(float x) {
#if __has_builtin(__builtin_amdgcn_exp2f)
  return __builtin_amdgcn_exp2f(x);
#else
  float r;
  asm("v_exp_f32 %0, %1" : "=v"(r) : "v"(x));
  return r;
#endif
}

// ---------------------------------------------------------------------------
// fp32 -> bf16 conversion pass (memory-bound, ~96 MB traffic)
// ---------------------------------------------------------------------------
struct CvtArgs {
  const float* src[7];
  unsigned short* dst[7];
  int n4[7];
};

__global__ __launch_bounds__(256) void cvt_bf16(CvtArgs c) {
  const int seg = blockIdx.y;
  const float* __restrict__ s = c.src[seg];
  unsigned short* __restrict__ d = c.dst[seg];
  const int n4 = c.n4[seg];
  for (int i = blockIdx.x * 256 + threadIdx.x; i < n4; i += gridDim.x * 256) {
    f32x4 v = reinterpret_cast<const f32x4*>(s)[i];
    short4v r;
    r[0] = (short)f2b(v[0]); r[1] = (short)f2b(v[1]);
    r[2] = (short)f2b(v[2]); r[3] = (short)f2b(v[3]);
    reinterpret_cast<short4v*>(d)[i] = r;
  }
}

// ---------------------------------------------------------------------------
// bf16 NT GEMM, 128x64 tile, BK=64 (16 K-steps: HALVED barrier-drain count
// vs r13's BK=32 -- r13 diagnosis: ~4800 cyc/step critical path is mostly
// the per-barrier vmcnt(0) drain; per-step issued work is ~500 cyc).
// 2-buffer global_load_lds staging (proven best engine, r9/r10/r14 all
// regressed vs it). LDS 48 KB -> 3 blocks/CU.
// 128B LDS rows (8 chunks): swizzle chunk ^= (row&7), applied on the
// pre-swizzled global SOURCE and on the ds_read offset (both-sides rule);
// each 8-lane ds_read phase covers all 8 chunks exactly once.
// T1 XCD clustering kept (FETCH 101->23 MB, round 13).
// C[row,col] = sum_k A[row,k]*W[col,k] + bia[col]
// ---------------------------------------------------------------------------
struct GB {
  const unsigned short* A[3];
  const unsigned short* W[3];
  const float* bia[3];
  void* out[3];
  int epi[3];   // 0=Q(scaled, exp2 domain) 1=K 2=V(transposed) 3=final(fp32)
};

__global__ __launch_bounds__(256, 3) void gemm_bf16(GB g) {
  // T1: xcd-contiguous remap; swz order [z][bm][bn], bn fastest.
  const int cpx = gridDim.x >> 3;
  const int swz = (blockIdx.x & 7) * cpx + (blockIdx.x >> 3);
  const int z   = swz >> 9;          // 512 blocks per z
  const int rem = swz & 511;
  const int bm  = rem >> 4, bn = rem & 15;

  const unsigned short* __restrict__ A = g.A[z];
  const unsigned short* __restrict__ W = g.W[z];
  const float* __restrict__ bia = g.bia[z];
  const int epi = g.epi[z];
  const int tid = threadIdx.x, lane = tid & 63, wid = tid >> 6;
  const int wr = wid >> 1, wc = wid & 1;          // 2x2 waves: 64x32 each
  const int fr = lane & 15, gq = lane >> 4;

  __shared__ unsigned short As[2][128][64];   // 16 KB x2
  __shared__ unsigned short Bs[2][64][64];    //  8 KB x2

  f32x4 acc[4][2] = {};

  // staging: 8 lanes per 128B row; row srow = lane>>3, chunk c8 = lane&7.
  // global source chunk pre-swizzled: c_src = c8 ^ (srow&7)  (srow+8k keeps
  // (row&7) invariant, so one pre-swizzle serves all call-sites).
  const int srow = lane >> 3;
  const int c8   = lane & 7;
  const int csrc = (c8 ^ (srow & 7)) * 16;
  const char* aS = (const char*)A + (size_t)(bm * 128 + wid * 32 + srow) * 2048 + csrc;
  const char* bS = (const char*)W + (size_t)(bn * 64 + wid * 16 + srow) * 2048 + csrc;

  auto stage = [&](int buf, int kt) {
    const int ko = kt * 128;   // byte offset within a 2048B row
    char* a0 = (char*)As[buf] + wid * 4096;
    char* b0 = (char*)Bs[buf] + wid * 2048;
    gload16(aS + ko, a0);
    gload16(aS + (size_t)8 * 2048 + ko, a0 + 1024);
    gload16(aS + (size_t)16 * 2048 + ko, a0 + 2048);
    gload16(aS + (size_t)24 * 2048 + ko, a0 + 3072);
    gload16(bS + ko, b0);
    gload16(bS + (size_t)8 * 2048 + ko, b0 + 1024);
  };

  // read chunk for k-half h: (4h+gq) ^ (fr&7)  (fragment-row base offsets
  // are multiples of 16, so row&7 == fr&7). ushort offset = chunk*8.
  int rdo[2];
#pragma unroll
  for (int h = 0; h < 2; ++h) rdo[h] = ((4 * h + gq) ^ (fr & 7)) * 8;

  stage(0, 0);
  __syncthreads();
  for (int kt = 0; kt < 16; ++kt) {
    const int buf = kt & 1;
    if (kt + 1 < 16) stage(buf ^ 1, kt + 1);
#pragma unroll
    for (int h = 0; h < 2; ++h) {
      short8 af[4], bf4[2];
#pragma unroll
      for (int i = 0; i < 4; ++i) af[i] = ld8(&As[buf][wr * 64 + i * 16 + fr][rdo[h]]);
#pragma unroll
      for (int j = 0; j < 2; ++j) bf4[j] = ld8(&Bs[buf][wc * 32 + j * 16 + fr][rdo[h]]);
#pragma unroll
      for (int i = 0; i < 4; ++i)
#pragma unroll
        for (int j = 0; j < 2; ++j)
          acc[i][j] = mfma16(af[i], bf4[j], acc[i][j]);
    }
    __syncthreads();
  }

#pragma unroll
  for (int i = 0; i < 4; ++i) {
#pragma unroll
    for (int j = 0; j < 2; ++j) {
#pragma unroll
      for (int r = 0; r < 4; ++r) {
        const int row = bm * 128 + wr * 64 + i * 16 + gq * 4 + r;
        const int col = bn * 64 + wc * 32 + j * 16 + fr;
        float v = acc[i][j][r] + bia[col];
        if (epi == 3) {
          ((float*)g.out[z])[(size_t)row * NDIM + col] = v;
        } else {
          const int b = row >> 11, s = row & (S_LEN - 1);
          const int h = col >> 6,  dh = col & (DHEAD - 1);
          unsigned short* O = (unsigned short*)g.out[z];
          if (epi == 0)      O[((size_t)(b * NHEAD + h) * S_LEN + s) * DHEAD + dh] = f2b(v * QSCALE);
          else if (epi == 1) O[((size_t)(b * NHEAD + h) * S_LEN + s) * DHEAD + dh] = f2b(v);
          else               O[((size_t)(b * NHEAD + h) * DHEAD + dh) * S_LEN + s] = f2b(v);
        }
      }
    }
  }
}

// ---------------------------------------------------------------------------
// Flash attention (round-12/13, passing, unchanged): split-KV x2 in-block,
// fixed m=0 log2-domain softmax with native v_exp, exact merge.
// ---------------------------------------------------------------------------
__global__ __launch_bounds__(512, 2) void attn_fwd(
    const unsigned short* __restrict__ Qp,
    const unsigned short* __restrict__ Kp,
    const unsigned short* __restrict__ Vt,
    unsigned short* __restrict__ AO) {
  const int nb = (blockIdx.x & 7) * 64 + (blockIdx.x >> 3);
  const int qt = nb & 15, bh = nb >> 4;
  const int tid = threadIdx.x, lane = tid & 63, wid = tid >> 6;
  const int qw = wid & 3, hw = wid >> 2;
  const int ql = lane & 31, hi = lane >> 5, l7 = lane & 7, l3 = lane >> 3;

  const unsigned short* Qh = Qp + (size_t)bh * S_LEN * DHEAD;
  const char* Kh = (const char*)(Kp + (size_t)bh * S_LEN * DHEAD);
  const char* Vh = (const char*)(Vt + (size_t)bh * DHEAD * S_LEN);

  __shared__ unsigned short Klds[2][2][4096];   // [hw][buf] 32KB
  __shared__ unsigned short Vlds[2][2][4096];   // [hw][buf] 32KB

  const int q0 = qt * 128 + qw * 32;
  short8 qf[4];
#pragma unroll
  for (int d16 = 0; d16 < 4; ++d16)
    qf[d16] = ld8(Qh + (size_t)(q0 + ql) * DHEAD + d16 * 16 + hi * 8);

  const int swc = (l7 ^ l3) << 4;
  const char* kS = Kh + (size_t)hw * 16 * 8192 + (qw * 16 + l3) * 128 + swc;
  const char* vS = Vh + (size_t)hw * 16 * 128 + (qw * 16 + l3) * 4096 + swc;
  char* kD0 = (char*)Klds[hw][0] + qw * 2048;
  char* vD0 = (char*)Vlds[hw][0] + qw * 2048;
  char* kD1 = (char*)Klds[hw][1] + qw * 2048;
  char* vD1 = (char*)Vlds[hw][1] + qw * 2048;

  int xo[4];
#pragma unroll
  for (int j = 0; j < 4; ++j) xo[j] = ((j * 2 + hi) ^ l7) << 4;

  float lacc[8] = {};
  f32x16 o0 = {}, o1 = {};

  gload16(kS, kD0); gload16(kS + 1024, kD0 + 1024);
  gload16(vS, vD0); gload16(vS + 32768, vD0 + 1024);
  __syncthreads();

  constexpr int NT = S_LEN / 64 / 2;   // 16 tiles per half
  for (int kt = 0; kt < NT; ++kt) {
    const int buf = kt & 1;
    if (kt + 1 < NT) {
      const char* kn = kS + (kt + 1) * 8192;
      const char* vn = vS + (kt + 1) * 128;
      char* kD = buf ? kD0 : kD1;
      char* vD = buf ? vD0 : vD1;
      gload16(kn, kD); gload16(kn + 1024, kD + 1024);
      gload16(vn, vD); gload16(vn + 32768, vD + 1024);
    }
    const char* kb = (const char*)Klds[hw][buf] + ql * 128;
    const char* vb = (const char*)Vlds[hw][buf] + ql * 128;

    f32x16 st0 = {}, st1 = {};
#pragma unroll
    for (int d16 = 0; d16 < 4; ++d16) {
      short8 k0 = ld8(kb + xo[d16]);
      short8 k1 = ld8(kb + 4096 + xo[d16]);
      st0 = mfma32(k0, qf[d16], st0);
      st1 = mfma32(k1, qf[d16], st1);
    }

    // P = 2^s (fixed m=0), lane-local l accumulation
#pragma unroll
    for (int r = 0; r < 16; ++r) {
      st0[r] = exp2n(st0[r]);
      st1[r] = exp2n(st1[r]);
    }
#pragma unroll
    for (int r = 0; r < 8; ++r)
      lacc[r] += (st0[r] + st0[r + 8]) + (st1[r] + st1[r + 8]);

#pragma unroll
    for (int ks = 0; ks < 4; ++ks) {
      const f32x16& p = (ks < 2) ? st0 : st1;
      const int a = 8 * (ks & 1);
      unsigned w0 = pk2(p[a + 0], p[a + 1]);
      unsigned w1 = pk2(p[a + 2], p[a + 3]);
      unsigned w2 = pk2(p[a + 4], p[a + 5]);
      unsigned w3 = pk2(p[a + 6], p[a + 7]);
      unsigned x0 = (unsigned)__shfl_xor((int)w0, 32);
      unsigned x1 = (unsigned)__shfl_xor((int)w1, 32);
      unsigned x2 = (unsigned)__shfl_xor((int)w2, 32);
      unsigned x3 = (unsigned)__shfl_xor((int)w3, 32);
      int4v pi;
      pi[0] = (int)(hi ? x2 : w0);
      pi[1] = (int)(hi ? x3 : w1);
      pi[2] = (int)(hi ? w2 : x0);
      pi[3] = (int)(hi ? w3 : x1);
      short8 pb = __builtin_bit_cast(short8, pi);
      short8 v0 = ld8(vb + xo[ks]);
      short8 v1 = ld8(vb + 4096 + xo[ks]);
      o0 = mfma32(v0, pb, o0);
      o1 = mfma32(v1, pb, o1);
    }
    __syncthreads();
  }

  // per-half l: tree over 8 + one cross-half exchange
#pragma unroll
  for (int s = 4; s; s >>= 1)
#pragma unroll
    for (int r = 0; r < s; ++r) lacc[r] += lacc[r + s];
  float l = lacc[0] + __shfl_xor(lacc[0], 32);

  // exact merge across KV halves: O = Oa + Ob, l = la + lb
  float* Kf = (float*)&Klds[0][0][0];
  float* Vf = (float*)&Vlds[0][0][0];
  if (hw == 1) {
#pragma unroll
    for (int r = 0; r < 16; ++r) {
      Kf[qw * 2048 + r * 64 + lane]        = o0[r];
      Kf[qw * 2048 + (16 + r) * 64 + lane] = o1[r];
    }
    Vf[qw * 64 + lane] = l;
  }
  __syncthreads();
  if (hw == 0) {
    const float inv = 1.f / (l + Vf[qw * 64 + lane]);
    const int b = bh >> 4, h = bh & 15;
    unsigned short* Op = AO + ((size_t)(b * S_LEN + q0 + ql)) * DMODEL + h * DHEAD;
#pragma unroll
    for (int gidx = 0; gidx < 4; ++gidx) {
      float f0[4], f1[4];
#pragma unroll
      for (int r = 0; r < 4; ++r) {
        const int rr = gidx * 4 + r;
        f0[r] = (o0[rr] + Kf[qw * 2048 + rr * 64 + lane]) * inv;
        f1[r] = (o1[rr] + Kf[qw * 2048 + (16 + rr) * 64 + lane]) * inv;
      }
      int2v s0, s1;
      s0[0] = (int)pk2(f0[0], f0[1]); s0[1] = (int)pk2(f0[2], f0[3]);
      s1[0] = (int)pk2(f1[0], f1[1]); s1[1] = (int)pk2(f1[2], f1[3]);
      *reinterpret_cast<int2v*>(Op + 8 * gidx + 4 * hi)      = s0;
      *reinterpret_cast<int2v*>(Op + 32 + 8 * gidx + 4 * hi) = s1;
    }
  }
}

extern "C" void kernel_launch(void* const* d_in, const int* in_sizes, int n_in,
                              void* d_out, int out_size, void* d_ws, size_t ws_size,
                              hipStream_t stream) {
  const float* query = (const float*)d_in[0];
  const float* key   = (const float*)d_in[1];
  const float* value = (const float*)d_in[2];
  const float* Wq = (const float*)d_in[3];  const float* bq = (const float*)d_in[4];
  const float* Wk = (const float*)d_in[5];  const float* bk = (const float*)d_in[6];
  const float* Wv = (const float*)d_in[7];  const float* bv = (const float*)d_in[8];
  const float* Wo = (const float*)d_in[9];  const float* bo = (const float*)d_in[10];

  const size_t MB = 1024u * 1024u;
  unsigned short* Xb  = (unsigned short*)((char*)d_ws + 0 * MB);
  unsigned short* Wb  = (unsigned short*)((char*)d_ws + 24 * MB);
  unsigned short* Wob = (unsigned short*)((char*)d_ws + 30 * MB);
  unsigned short* Qp  = (unsigned short*)((char*)d_ws + 32 * MB);
  unsigned short* Kp  = (unsigned short*)((char*)d_ws + 40 * MB);
  unsigned short* Vt  = (unsigned short*)((char*)d_ws + 48 * MB);
  unsigned short* AOb = (unsigned short*)((char*)d_ws + 0 * MB);   // overlays Xb[query]

  const int NACT = MROWS * DMODEL;
  const int NWT  = DMODEL * DMODEL;

  CvtArgs ca;
  ca.src[0] = query; ca.dst[0] = Xb;            ca.n4[0] = NACT / 4;
  ca.src[1] = key;   ca.dst[1] = Xb + NACT;     ca.n4[1] = NACT / 4;
  ca.src[2] = value; ca.dst[2] = Xb + 2 * NACT; ca.n4[2] = NACT / 4;
  ca.src[3] = Wq;    ca.dst[3] = Wb;            ca.n4[3] = NWT / 4;
  ca.src[4] = Wk;    ca.dst[4] = Wb + NWT;      ca.n4[4] = NWT / 4;
  ca.src[5] = Wv;    ca.dst[5] = Wb + 2 * NWT;  ca.n4[5] = NWT / 4;
  ca.src[6] = Wo;    ca.dst[6] = Wob;           ca.n4[6] = NWT / 4;
  cvt_bf16<<<dim3(512, 7), 256, 0, stream>>>(ca);

  GB g1;
  g1.A[0] = Xb;            g1.A[1] = Xb + NACT; g1.A[2] = Xb + 2 * NACT;
  g1.W[0] = Wb;            g1.W[1] = Wb + NWT;  g1.W[2] = Wb + 2 * NWT;
  g1.bia[0] = bq;  g1.bia[1] = bk; g1.bia[2] = bv;
  g1.out[0] = Qp;  g1.out[1] = Kp; g1.out[2] = Vt;
  g1.epi[0] = 0;   g1.epi[1] = 1;  g1.epi[2] = 2;
  gemm_bf16<<<dim3(16 * 32 * 3), 256, 0, stream>>>(g1);

  attn_fwd<<<dim3(BHN * 16), 512, 0, stream>>>(Qp, Kp, Vt, AOb);

  GB g2 = {};
  g2.A[0] = AOb; g2.W[0] = Wob; g2.bia[0] = bo; g2.out[0] = d_out; g2.epi[0] = 3;
  gemm_bf16<<<dim3(16 * 32), 256, 0, stream>>>(g2);
}